// Round 7
// baseline (122.249 us; speedup 1.0000x reference)
//
#include <hip/hip_runtime.h>
#include <hip/hip_bf16.h>

// Problem: B=2, DIM=512, NUM_HEADS=1, tokens TOK=256 (16x16 window, w=1).
// K1 (256 blocks x 512 thr = 1 block/CU, 8 waves): block owns (b, 4 channels).
//   GEMM: wave w = c-64-slice, all 12 qkv rows in regs (weights via uniform
//   s_loads, x float4 from L2, register prefetch). 2-stage LDS reduce (6 rows
//   per stage, red[8][6][256]=48KB staged twice) -> qs/ks/vs.
//   Attention: waves = (channel 0..3, g-half); bias via 7-float register
//   window from the 61-entry tab (conflict-free b32), NO brow matrix (R6's
//   2.7M bank-conflict cycles came from brow b64 reads).
//   lpart/apart alias the dead red region. LDS total 60.3 KB.
// K2 (256 blocks x 256 thr): proj rows o0..o0+3, c-quarter waves, LDS reduce,
//   register prefetch, writes d_out directly. Workspace: aout only (1 MB).

#define TOK   256
#define KDIM  512
#define LOG2E 1.4426950408889634f
#define SCALE 0.04419417382415922f   // 512^{-1/2}

// v_exp_f32 (base-2) — __exp2f collides with glibc math.h, use the builtin.
#define EXP2(x) __builtin_amdgcn_exp2f(x)

struct K1Smem {
    union {
        float red[8][6][256];                              // 48 KB (2 stages)
        struct { float lpart[4][256], apart[4][256]; } mg; // 8 KB (after red)
    } u;
    float stab[64];        // rpb window table * log2e (61 used)
    float qs_[4][256];     // q + bias
    float ks_[4][256];     // (k + bias) * scale * log2e
    float vs_[4][256];     // v + bias
};

__global__ __launch_bounds__(512, 2)
void qkv_attn(const float* __restrict__ x, const float* __restrict__ qkv_w,
              const float* __restrict__ qkv_b, const float* __restrict__ rpb,
              float* __restrict__ aout)
{
    __shared__ K1Smem sm;
    const int t    = threadIdx.x;
    const int w    = t >> 6;          // wave 0..7
    const int lane = t & 63;
    const int d0   = blockIdx.x * 4;  // 4 channels
    const int b    = blockIdx.y;
    const int g0   = lane * 4;

    // bias table: tab[j] = rpb[mod(j-30, 961)] * log2e, j in 0..60
    if (t < 61) {
        const int rel = t - 30;
        sm.stab[t] = rpb[rel < 0 ? rel + 961 : rel] * LOG2E;
    }

    // ---- GEMM: 12 qkv rows x 4 g, K-slice [64w, 64w+64), reg prefetch ----
    float acc[12][4];
#pragma unroll
    for (int e = 0; e < 12; ++e)
#pragma unroll
        for (int j = 0; j < 4; ++j) acc[e][j] = 0.f;
    {
        const float* xb = x + (size_t)b * (KDIM * TOK);
        const int cbeg = w * 64;
        float4 xv[4], xn[4];
#pragma unroll
        for (int u = 0; u < 4; ++u)
            xv[u] = *(const float4*)(xb + (size_t)(cbeg + u) * TOK + g0);
#pragma unroll 1
        for (int it = 0; it < 16; ++it) {
            const int c = cbeg + it * 4;
            if (it < 15) {
#pragma unroll
                for (int u = 0; u < 4; ++u)
                    xn[u] = *(const float4*)(xb + (size_t)(c + 4 + u) * TOK + g0);
            }
#pragma unroll
            for (int e = 0; e < 12; ++e) {
                // wave-uniform weight quad -> s_load_dwordx4
                const float4 wv = *(const float4*)(
                    qkv_w + (size_t)((e >> 2) * 512 + d0 + (e & 3)) * KDIM + c);
                acc[e][0] = fmaf(wv.x, xv[0].x, acc[e][0]);
                acc[e][1] = fmaf(wv.x, xv[0].y, acc[e][1]);
                acc[e][2] = fmaf(wv.x, xv[0].z, acc[e][2]);
                acc[e][3] = fmaf(wv.x, xv[0].w, acc[e][3]);
                acc[e][0] = fmaf(wv.y, xv[1].x, acc[e][0]);
                acc[e][1] = fmaf(wv.y, xv[1].y, acc[e][1]);
                acc[e][2] = fmaf(wv.y, xv[1].z, acc[e][2]);
                acc[e][3] = fmaf(wv.y, xv[1].w, acc[e][3]);
                acc[e][0] = fmaf(wv.z, xv[2].x, acc[e][0]);
                acc[e][1] = fmaf(wv.z, xv[2].y, acc[e][1]);
                acc[e][2] = fmaf(wv.z, xv[2].z, acc[e][2]);
                acc[e][3] = fmaf(wv.z, xv[2].w, acc[e][3]);
                acc[e][0] = fmaf(wv.w, xv[3].x, acc[e][0]);
                acc[e][1] = fmaf(wv.w, xv[3].y, acc[e][1]);
                acc[e][2] = fmaf(wv.w, xv[3].z, acc[e][2]);
                acc[e][3] = fmaf(wv.w, xv[3].w, acc[e][3]);
            }
#pragma unroll
            for (int u = 0; u < 4; ++u) xv[u] = xn[u];
        }
    }

    // ---- 2-stage reduce: rows [6s, 6s+6) across the 8 c-slices ----
    const int gred = t & 255;
    const int esub = t >> 8;          // wave-uniform (waves 0-3 vs 4-7)
#pragma unroll
    for (int s = 0; s < 2; ++s) {
        if (s) __syncthreads();       // stage-0 readers done before overwrite
#pragma unroll
        for (int el = 0; el < 6; ++el)
            *(float4*)&sm.u.red[w][el][g0] =
                make_float4(acc[s * 6 + el][0], acc[s * 6 + el][1],
                            acc[s * 6 + el][2], acc[s * 6 + el][3]);
        __syncthreads();
#pragma unroll
        for (int j = 0; j < 3; ++j) {
            const int el = esub * 3 + j;
            float sum = 0.f;
#pragma unroll
            for (int p = 0; p < 8; ++p) sum += sm.u.red[p][el][gred];
            const int e = s * 6 + el;           // wave-uniform
            const int type = e >> 2, ch = e & 3;
            if (type == 0)
                sm.qs_[ch][gred] = sum + qkv_b[d0 + ch];
            else if (type == 1)
                sm.ks_[ch][gred] = (sum + qkv_b[512 + d0 + ch]) * (SCALE * LOG2E);
            else
                sm.vs_[ch][gred] = sum + qkv_b[1024 + d0 + ch];
        }
    }
    __syncthreads();

    // ---- attention: wave = (dl channel, gh g-half); lane owns h-quad ----
    const int dl  = w & 3;
    const int gh  = w >> 2;
    const int h0  = lane * 4;
    const int rh0 = (lane >> 2) + 4 * (lane & 3);   // r(h0); r(h0+r)=rh0+r

    float q[4];
    {
        const float4 q4 = *(const float4*)&sm.qs_[dl][h0];
        q[0] = q4.x; q[1] = q4.y; q[2] = q4.z; q[3] = q4.w;
    }

    float l[4]  = {0.f, 0.f, 0.f, 0.f};
    float am[4] = {0.f, 0.f, 0.f, 0.f};
    const int pbeg = gh * 128;
#pragma unroll 2
    for (int p = pbeg; p < pbeg + 128; p += 4) {
        const float4 k4 = *(const float4*)&sm.ks_[dl][p];   // bcast
        const float4 v4 = *(const float4*)&sm.vs_[dl][p];   // bcast
        // 7-float bias window: bias[h0+r][p+j] = f[3 + r - j]
        const int i0 = rh0 + 30 - ((p >> 4) + (p & 15));
        float f[7];
#pragma unroll
        for (int k = 0; k < 7; ++k) f[k] = sm.stab[i0 - 3 + k];
#pragma unroll
        for (int r = 0; r < 4; ++r) {
            float e;
            e = EXP2(fmaf(q[r], k4.x, f[3 + r])); l[r] += e; am[r] = fmaf(e, v4.x, am[r]);
            e = EXP2(fmaf(q[r], k4.y, f[2 + r])); l[r] += e; am[r] = fmaf(e, v4.y, am[r]);
            e = EXP2(fmaf(q[r], k4.z, f[1 + r])); l[r] += e; am[r] = fmaf(e, v4.z, am[r]);
            e = EXP2(fmaf(q[r], k4.w, f[0 + r])); l[r] += e; am[r] = fmaf(e, v4.w, am[r]);
        }
    }

    // merge the two g-halves (additive: no max-subtraction, scores ~<=1.1)
    if (gh == 1) {
        *(float4*)&sm.u.mg.lpart[dl][h0] = make_float4(l[0], l[1], l[2], l[3]);
        *(float4*)&sm.u.mg.apart[dl][h0] = make_float4(am[0], am[1], am[2], am[3]);
    }
    __syncthreads();
    if (gh == 0) {
        const float4 lo = *(const float4*)&sm.u.mg.lpart[dl][h0];
        const float4 ao = *(const float4*)&sm.u.mg.apart[dl][h0];
        float4 o4;
        o4.x = (am[0] + ao.x) / (l[0] + lo.x);
        o4.y = (am[1] + ao.y) / (l[1] + lo.y);
        o4.z = (am[2] + ao.z) / (l[2] + lo.z);
        o4.w = (am[3] + ao.w) / (l[3] + lo.w);
        *(float4*)(aout + ((size_t)b * 512 + d0 + dl) * TOK + h0) = o4;
    }
}

// ---------------------------------------------------------------------------
// K2: proj rows o0..o0+3, c-quarter per wave, LDS reduce, + bias -> d_out.
// ---------------------------------------------------------------------------
__global__ __launch_bounds__(256)
void proj_fused(const float* __restrict__ aout, const float* __restrict__ proj_w,
                const float* __restrict__ proj_b, float* __restrict__ out)
{
    __shared__ float sred[4][4][256];   // 16 KB
    const int t  = threadIdx.x;
    const int o0 = blockIdx.x * 4;
    const int b  = blockIdx.y;
    const int w  = t >> 6;
    const int g0 = (t & 63) * 4;

    const float* ab = aout + (size_t)b * (KDIM * TOK);

    float acc[4][4];
#pragma unroll
    for (int e = 0; e < 4; ++e)
#pragma unroll
        for (int j = 0; j < 4; ++j) acc[e][j] = 0.f;

    const int cbeg = w * 128;
    float4 av[4], an[4];
#pragma unroll
    for (int u = 0; u < 4; ++u)
        av[u] = *(const float4*)(ab + (size_t)(cbeg + u) * TOK + g0);
#pragma unroll 1
    for (int it = 0; it < 32; ++it) {
        const int c = cbeg + it * 4;
        if (it < 31) {
#pragma unroll
            for (int u = 0; u < 4; ++u)
                an[u] = *(const float4*)(ab + (size_t)(c + 4 + u) * TOK + g0);
        }
#pragma unroll
        for (int e = 0; e < 4; ++e) {
            const float4 wv = *(const float4*)(proj_w + (size_t)(o0 + e) * KDIM + c);
            acc[e][0] = fmaf(wv.x, av[0].x, acc[e][0]);
            acc[e][1] = fmaf(wv.x, av[0].y, acc[e][1]);
            acc[e][2] = fmaf(wv.x, av[0].z, acc[e][2]);
            acc[e][3] = fmaf(wv.x, av[0].w, acc[e][3]);
            acc[e][0] = fmaf(wv.y, av[1].x, acc[e][0]);
            acc[e][1] = fmaf(wv.y, av[1].y, acc[e][1]);
            acc[e][2] = fmaf(wv.y, av[1].z, acc[e][2]);
            acc[e][3] = fmaf(wv.y, av[1].w, acc[e][3]);
            acc[e][0] = fmaf(wv.z, av[2].x, acc[e][0]);
            acc[e][1] = fmaf(wv.z, av[2].y, acc[e][1]);
            acc[e][2] = fmaf(wv.z, av[2].z, acc[e][2]);
            acc[e][3] = fmaf(wv.z, av[2].w, acc[e][3]);
            acc[e][0] = fmaf(wv.w, av[3].x, acc[e][0]);
            acc[e][1] = fmaf(wv.w, av[3].y, acc[e][1]);
            acc[e][2] = fmaf(wv.w, av[3].z, acc[e][2]);
            acc[e][3] = fmaf(wv.w, av[3].w, acc[e][3]);
        }
#pragma unroll
        for (int u = 0; u < 4; ++u) av[u] = an[u];
    }
#pragma unroll
    for (int e = 0; e < 4; ++e)
        *(float4*)&sred[w][e][g0] = make_float4(acc[e][0], acc[e][1],
                                                acc[e][2], acc[e][3]);
    __syncthreads();

#pragma unroll
    for (int e = 0; e < 4; ++e) {
        const float v = sred[0][e][t] + sred[1][e][t] +
                        sred[2][e][t] + sred[3][e][t] + proj_b[o0 + e];
        out[((size_t)b * 512 + o0 + e) * TOK + t] = v;
    }
}

// ---------------------------------------------------------------------------
extern "C" void kernel_launch(void* const* d_in, const int* in_sizes, int n_in,
                              void* d_out, int out_size, void* d_ws, size_t ws_size,
                              hipStream_t stream)
{
    const float* x      = (const float*)d_in[0];   // [2][512][256]
    const float* qkv_w  = (const float*)d_in[1];   // [1536][512]
    const float* qkv_b  = (const float*)d_in[2];   // [1536]
    const float* proj_w = (const float*)d_in[3];   // [512][512]
    const float* proj_b = (const float*)d_in[4];   // [512]
    const float* rpb    = (const float*)d_in[5];   // [961]
    float* out  = (float*)d_out;                   // [2][512][256]
    float* aout = (float*)d_ws;                    // 262,144 floats (1 MB)

    // K1: fused qkv + attention. grid (4ch-groups=128, b=2) = 256 blocks (1/CU)
    qkv_attn<<<dim3(128, 2), 512, 0, stream>>>(x, qkv_w, qkv_b, rpb, aout);

    // K2: fused proj + bias. grid (o-tiles=128, b=2) = 256 blocks (1/CU)
    proj_fused<<<dim3(128, 2), 256, 0, stream>>>(aout, proj_w, proj_b, out);
}